// Round 13
// baseline (1586.026 us; speedup 1.0000x reference)
//
#include <hip/hip_runtime.h>
#include <math.h>

#define NPROTO 8
#define KV_NCH 4
#define MSG_NCH 8
#define MBIG (1L << 40)

typedef __attribute__((ext_vector_type(8))) short short8;
typedef __attribute__((ext_vector_type(4))) float floatx4;

static __device__ __forceinline__ ushort f2b(float f) {
    unsigned u = __builtin_bit_cast(unsigned, f);
    unsigned r = (u + 0x7fffu + ((u >> 16) & 1u)) >> 16;
    return (ushort)r;
}

static __device__ __forceinline__ float b2f(ushort u) {
    return __builtin_bit_cast(float, ((unsigned)u) << 16);
}

typedef __attribute__((address_space(1))) void gvoid;
typedef __attribute__((address_space(3))) void lvoid;

// async global->LDS, 16B per lane. LDS dest must be lane-contiguous per wave.
static __device__ __forceinline__ void gload_lds16(const ushort* g, ushort* l) {
    __builtin_amdgcn_global_load_lds((gvoid*)(void*)g, (lvoid*)l, 16, 0, 0);
}

// ---------------- prototype projection / argmax-class kernel ----------------
__global__ __launch_bounds__(256) void lft_class_kernel(
    const float* __restrict__ f0wo, const float* __restrict__ f1wo,
    const int* __restrict__ mask0, const int* __restrict__ mask1,
    const float* __restrict__ proto,
    float* out, int* cls0, int* cls1)
{
    __shared__ float pr[2048];
    int t = threadIdx.x;
    *(float4*)&pr[t * 4]        = *(const float4*)&proto[t * 4];
    *(float4*)&pr[1024 + t * 4] = *(const float4*)&proto[1024 + t * 4];
    __syncthreads();
    int wave = t >> 6, lane = t & 63;
    long token = (long)blockIdx.x * 4 + wave;
    const float* fsrc; const int* msrc; float* fpout; float* clsout; int* clsarr; long tok;
    if (token < 38400) {
        tok = token; fsrc = f0wo; msrc = mask0;
        fpout = out + 19737600L; clsout = out + 19660800L; clsarr = cls0;
    } else {
        tok = token - 38400; fsrc = f1wo; msrc = mask1;
        fpout = out + 20044800L; clsout = out + 19699200L; clsarr = cls1;
    }
    float4 f = *(const float4*)&fsrc[tok * 256 + lane * 4];
    float s[NPROTO];
#pragma unroll
    for (int p = 0; p < NPROTO; p++) {
        float4 pv = *(const float4*)&pr[p * 256 + lane * 4];
        s[p] = f.x * pv.x + f.y * pv.y + f.z * pv.z + f.w * pv.w;
    }
    float k0_ = (lane & 1) ? s[4] : s[0], d0 = (lane & 1) ? s[0] : s[4];
    float k1_ = (lane & 1) ? s[5] : s[1], d1 = (lane & 1) ? s[1] : s[5];
    float k2_ = (lane & 1) ? s[6] : s[2], d2 = (lane & 1) ? s[2] : s[6];
    float k3_ = (lane & 1) ? s[7] : s[3], d3 = (lane & 1) ? s[3] : s[7];
    float w0 = k0_ + __shfl_xor(d0, 1, 64);
    float w1 = k1_ + __shfl_xor(d1, 1, 64);
    float w2 = k2_ + __shfl_xor(d2, 1, 64);
    float w3 = k3_ + __shfl_xor(d3, 1, 64);
    float u0k = (lane & 2) ? w2 : w0, u0d = (lane & 2) ? w0 : w2;
    float u1k = (lane & 2) ? w3 : w1, u1d = (lane & 2) ? w1 : w3;
    float x0 = u0k + __shfl_xor(u0d, 2, 64);
    float x1 = u1k + __shfl_xor(u1d, 2, 64);
    float yk = (lane & 4) ? x1 : x0, yd = (lane & 4) ? x0 : x1;
    float sc = yk + __shfl_xor(yd, 4, 64);
    sc += __shfl_xor(sc, 8, 64);
    sc += __shfl_xor(sc, 16, 64);
    sc += __shfl_xor(sc, 32, 64);
    int p = ((lane & 1) << 2) | (lane & 2) | ((lane >> 2) & 1);
    if (lane < 8) fpout[tok * 8 + p] = sc;
    float bv = sc; int bi = p;
#pragma unroll
    for (int o = 1; o < 8; o <<= 1) {
        float ov = __shfl_xor(bv, o, 64);
        int oi = __shfl_xor(bi, o, 64);
        if (ov > bv || (ov == bv && oi < bi)) { bv = ov; bi = oi; }
    }
    if (lane == 0) {
        clsout[tok] = (float)bi;
        clsarr[tok] = msrc[tok] ? bi : -1;
    }
}

// ---------------- counting sort of tokens by (batch,class) -------------------
__global__ __launch_bounds__(256) void lft_sort_kernel(
    const int* __restrict__ cls0, const int* __restrict__ cls1,
    int* tl0, int* tl1, int* meta)
{
    int g = blockIdx.x; int L = g >> 3, b = g & 7;
    const int* cls = (L ? cls1 : cls0) + b * 4800;
    int* tl = (L ? tl1 : tl0) + b * 4800;
    int* mt = meta + (L * 8 + b) * 16;
    __shared__ int cnt[8], base[8], pos[8];
    int t = threadIdx.x;
    if (t < 8) cnt[t] = 0;
    __syncthreads();
    for (int tok = t; tok < 4800; tok += 256) {
        int c = cls[tok];
        if (c >= 0) atomicAdd(&cnt[c], 1);
    }
    __syncthreads();
    if (t == 0) {
        int s = 0;
        for (int c = 0; c < 8; c++) { base[c] = s; pos[c] = s; s += cnt[c]; }
    }
    __syncthreads();
    if (t < 8) { mt[t * 2] = base[t]; mt[t * 2 + 1] = cnt[t]; }
    for (int tok = t; tok < 4800; tok += 256) {
        int c = cls[tok];
        if (c >= 0) { int p = atomicAdd(&pos[c], 1); tl[p] = tok; }
    }
}

// ---------------- weight convert + transpose: Wt[n*K+k] = bf16(W[k*N+n]) ----
__global__ __launch_bounds__(256) void lft_wconv_kernel(
    const float* W0, const float* W1p, const float* W2p, const float* W3p,
    int K, int N, int nTypes, ushort* dst)
{
    int z = blockIdx.z;
    int li = z / nTypes, mi = z % nTypes;
    const float* srcs[4] = {W0, W1p, W2p, W3p};
    const float* src = srcs[mi] + (size_t)li * K * N;
    ushort* outp = dst + (size_t)z * K * N;
    __shared__ float tile[32][33];
    int k0 = blockIdx.x * 32, n0 = blockIdx.y * 32;
    int t = threadIdx.x;
    int r = t >> 3, c4 = (t & 7) << 2;
    float4 v = *(const float4*)&src[(size_t)(k0 + r) * N + n0 + c4];
    tile[r][c4] = v.x; tile[r][c4 + 1] = v.y; tile[r][c4 + 2] = v.z; tile[r][c4 + 3] = v.w;
    __syncthreads();
    ushort4 o;
    o.x = f2b(tile[c4 + 0][r]);
    o.y = f2b(tile[c4 + 1][r]);
    o.z = f2b(tile[c4 + 2][r]);
    o.w = f2b(tile[c4 + 3][r]);
    *(ushort4*)&outp[(size_t)(n0 + r) * K + k0 + c4] = o;
}

// ---------------- bf16 cast of feat0/feat1 (shadows only) ----------------
__global__ __launch_bounds__(256) void lft_cast_kernel(
    const float* __restrict__ f0, const float* __restrict__ f1,
    ushort* fab, ushort* fbb)
{
    long idx = ((long)blockIdx.x * 256 + threadIdx.x) * 4;
    const float* src; ushort* db; long o;
    if (idx < 9830400L) { src = f0; db = fab; o = idx; }
    else                { src = f1; db = fbb; o = idx - 9830400L; }
    float4 v = *(const float4*)&src[o];
    ushort4 u; u.x = f2b(v.x); u.y = f2b(v.y); u.z = f2b(v.z); u.w = f2b(v.w);
    *(ushort4*)&db[o] = u;
}

// ---------------- bf16 MFMA GEMM, 2-phase pipelined: C = act([A0|A1] @ Wt^T) -
// 128x128 tile, BK=32, dbuf LDS, gload_lds dwordx4, counted vmcnt(4).
// Source-col swizzle (rule #21), XCD remap (T1), transposed-operand vectorized
// epilogue. Split output by n0 (Cb2/colSplit). M-CONCAT (A0b/A1b/mHalf):
// blocks with m0>=mHalf read the second tensor pair (local rows), write C at
// GLOBAL rows -> two independent problems fused into one dispatch.
__global__ __launch_bounds__(256) void lft_mfma_gemm(
    const ushort* __restrict__ A0, const ushort* __restrict__ A1, int kSplit,
    const ushort* __restrict__ Wt,
    float* Cf, ushort* Cb, int N, int K, int act, int actSplit,
    ushort* Cb2, int N2, int colSplit,
    const ushort* A0b, const ushort* A1b, long mHalf)
{
    __shared__ ushort As[2][128 * 32];
    __shared__ ushort Bs[2][128 * 32];
    int t = threadIdx.x;
    int nbx = gridDim.x;
    int nwg = nbx * gridDim.y;
    int orig = blockIdx.y * nbx + blockIdx.x;
    int q8 = nwg >> 3;
    int swz = (nwg & 7) ? orig : ((orig & 7) * q8 + (orig >> 3));
    int bx = swz % nbx, by = swz / nbx;
    long mg0 = (long)by << 7;          // global output row base
    int n0 = bx << 7;
    const ushort* pA0 = A0; const ushort* pA1 = A1;
    long m0 = mg0;                     // local input row base
    if (mg0 >= mHalf) { pA0 = A0b; pA1 = A1b; m0 = mg0 - mHalf; }
    int wave = t >> 6, lane = t & 63;
    int wm = wave >> 1, wn = wave & 1;
    int l16 = lane & 15, quad = lane >> 4;
    int r = t >> 2;
    int cu = (t & 3) << 3;
    int fso = (((t & 3) ^ ((r ^ (r >> 2)) & 3)) << 3);
    floatx4 acc[4][4] = {};

    auto stage = [&](int buf, int k0) {
        const ushort* Asrc; int kcol, ldA;
        if (k0 < kSplit) { Asrc = pA0; kcol = k0;          ldA = kSplit; }
        else             { Asrc = pA1; kcol = k0 - kSplit; ldA = K - kSplit; }
        gload_lds16(&Asrc[(m0 + r) * ldA + kcol + fso],      &As[buf][r * 32 + cu]);
        gload_lds16(&Asrc[(m0 + r + 64) * ldA + kcol + fso], &As[buf][(r + 64) * 32 + cu]);
        gload_lds16(&Wt[(size_t)(n0 + r) * K + k0 + fso],    &Bs[buf][r * 32 + cu]);
        gload_lds16(&Wt[(size_t)(n0 + r + 64) * K + k0 + fso], &Bs[buf][(r + 64) * 32 + cu]);
    };

    int qs = ((quad ^ ((l16 ^ (l16 >> 2)) & 3)) << 3);
    stage(0, 0);
    int cur = 0;
    for (int k0 = 0; k0 < K; k0 += 32) {
        if (k0 + 32 < K) {
            stage(cur ^ 1, k0 + 32);
            asm volatile("s_waitcnt vmcnt(4)" ::: "memory");
        } else {
            asm volatile("s_waitcnt vmcnt(0)" ::: "memory");
        }
        __builtin_amdgcn_s_barrier();
        short8 af[4], bfr[4];
#pragma unroll
        for (int i = 0; i < 4; i++) {
            af[i]  = *(const short8*)&As[cur][(wm * 64 + i * 16 + l16) * 32 + qs];
            bfr[i] = *(const short8*)&Bs[cur][(wn * 64 + i * 16 + l16) * 32 + qs];
        }
#pragma unroll
        for (int i = 0; i < 4; i++)
#pragma unroll
            for (int j = 0; j < 4; j++)
                acc[i][j] = __builtin_amdgcn_mfma_f32_16x16x32_bf16(bfr[j], af[i], acc[i][j], 0, 0, 0);
        asm volatile("" ::: "memory");
        __builtin_amdgcn_s_barrier();
        cur ^= 1;
    }
    int effAct = (n0 >= actSplit) ? 0 : act;
    float* Cfp = Cf;
    ushort* Cbp = Cb;
    int ldC = N, cb0 = n0;
    if (Cb2 && n0 >= colSplit) { Cbp = Cb2; Cfp = nullptr; ldC = N2; cb0 = n0 - colSplit; }
#pragma unroll
    for (int i = 0; i < 4; i++) {
        long rowb = mg0 + wm * 64 + i * 16 + l16;
#pragma unroll
        for (int j = 0; j < 4; j++) {
            int colb = cb0 + wn * 64 + j * 16 + quad * 4;
            float v0 = acc[i][j][0], v1 = acc[i][j][1], v2 = acc[i][j][2], v3 = acc[i][j][3];
            if (effAct == 1) {
                v0 = v0 > 0.f ? v0 + 1.f : __expf(v0);
                v1 = v1 > 0.f ? v1 + 1.f : __expf(v1);
                v2 = v2 > 0.f ? v2 + 1.f : __expf(v2);
                v3 = v3 > 0.f ? v3 + 1.f : __expf(v3);
            } else if (effAct == 2) {
                v0 = fmaxf(v0, 0.f); v1 = fmaxf(v1, 0.f);
                v2 = fmaxf(v2, 0.f); v3 = fmaxf(v3, 0.f);
            }
            if (Cfp) {
                float4 f4; f4.x = v0; f4.y = v1; f4.z = v2; f4.w = v3;
                *(float4*)&Cfp[rowb * ldC + colb] = f4;
            }
            if (Cbp) {
                ushort4 u4;
                u4.x = f2b(v0); u4.y = f2b(v1); u4.z = f2b(v2); u4.w = f2b(v3);
                *(ushort4*)&Cbp[rowb * ldC + colb] = u4;
            }
        }
    }
}

// ---------------- fused GEMM (N=256 full-row) + LayerNorm epilogue -----------
// 64x256 tile, BK=32, 4 waves (1x4 col-quarters, 64x64 per wave). M-CONCAT:
// blocks with mg0>=mHalf switch to the "b" pointer set with local rows.
__global__ __launch_bounds__(256) void lft_gemm_ln(
    const ushort* A, const ushort* Ab, const ushort* __restrict__ Wt, int K,
    const float* __restrict__ g, const float* __restrict__ bb,
    const float* resid, const float* residb,
    const int* cls, const int* clsb,
    float* outF, float* outFb,
    ushort* outB, ushort* outBb, long mHalf)
{
    __shared__ ushort As[2][64 * 32];
    __shared__ ushort Bs[2][256 * 32];
    __shared__ float red[4][64][2];
    int t = threadIdx.x;
    long mg0 = (long)blockIdx.x << 6;
    long m0 = mg0;
    if (mg0 >= mHalf) {
        A = Ab; resid = residb; cls = clsb; outF = outFb; outB = outBb;
        m0 = mg0 - mHalf;
    }
    int wave = t >> 6, lane = t & 63;
    int wn = wave;
    int l16 = lane & 15, quad = lane >> 4;
    int r = t >> 2;
    int cu = (t & 3) << 3;
    int fso = (((t & 3) ^ ((r ^ (r >> 2)) & 3)) << 3);
    floatx4 acc[4][4] = {};

    auto stage = [&](int buf, int k0) {
        gload_lds16(&A[(m0 + r) * K + k0 + fso], &As[buf][r * 32 + cu]);
#pragma unroll
        for (int s = 0; s < 4; s++)
            gload_lds16(&Wt[(size_t)(s * 64 + r) * K + k0 + fso],
                        &Bs[buf][(s * 64 + r) * 32 + cu]);
    };

    int qs = ((quad ^ ((l16 ^ (l16 >> 2)) & 3)) << 3);
    stage(0, 0);
    int cur = 0;
    for (int k0 = 0; k0 < K; k0 += 32) {
        if (k0 + 32 < K) {
            stage(cur ^ 1, k0 + 32);
            asm volatile("s_waitcnt vmcnt(5)" ::: "memory");
        } else {
            asm volatile("s_waitcnt vmcnt(0)" ::: "memory");
        }
        __builtin_amdgcn_s_barrier();
        short8 af[4], bfr[4];
#pragma unroll
        for (int i = 0; i < 4; i++) {
            af[i]  = *(const short8*)&As[cur][(i * 16 + l16) * 32 + qs];
            bfr[i] = *(const short8*)&Bs[cur][(wn * 64 + i * 16 + l16) * 32 + qs];
        }
#pragma unroll
        for (int i = 0; i < 4; i++)
#pragma unroll
            for (int j = 0; j < 4; j++)
                acc[i][j] = __builtin_amdgcn_mfma_f32_16x16x32_bf16(bfr[j], af[i], acc[i][j], 0, 0, 0);
        asm volatile("" ::: "memory");
        __builtin_amdgcn_s_barrier();
        cur ^= 1;
    }
#pragma unroll
    for (int i = 0; i < 4; i++) {
        float s = 0.f, sq = 0.f;
#pragma unroll
        for (int j = 0; j < 4; j++)
#pragma unroll
            for (int rr = 0; rr < 4; rr++) { float v = acc[i][j][rr]; s += v; sq += v * v; }
        s  += __shfl_xor(s, 16, 64);  sq += __shfl_xor(sq, 16, 64);
        s  += __shfl_xor(s, 32, 64);  sq += __shfl_xor(sq, 32, 64);
        if (quad == 0) {
            int rl = i * 16 + l16;
            red[wn][rl][0] = s;
            red[wn][rl][1] = sq;
        }
    }
    __syncthreads();
#pragma unroll
    for (int i = 0; i < 4; i++) {
        int rl = i * 16 + l16;
        long row = m0 + rl;
        float tsum = red[0][rl][0] + red[1][rl][0] + red[2][rl][0] + red[3][rl][0];
        float tsq  = red[0][rl][1] + red[1][rl][1] + red[2][rl][1] + red[3][rl][1];
        float mean = tsum * (1.0f / 256.0f);
        float var  = tsq * (1.0f / 256.0f) - mean * mean;
        float rsq  = rsqrtf(var + 1e-5f);
        bool keep = true;
        if (cls) keep = (cls[row] >= 0);
#pragma unroll
        for (int j = 0; j < 4; j++) {
            int col = wn * 64 + j * 16 + quad * 4;
            float4 gv = *(const float4*)&g[col];
            float4 bv = *(const float4*)&bb[col];
            float y0 = (acc[i][j][0] - mean) * rsq * gv.x + bv.x;
            float y1 = (acc[i][j][1] - mean) * rsq * gv.y + bv.y;
            float y2 = (acc[i][j][2] - mean) * rsq * gv.z + bv.z;
            float y3 = (acc[i][j][3] - mean) * rsq * gv.w + bv.w;
            if (resid) {
                float4 xr = *(const float4*)&resid[row * 256 + col];
                if (keep) { y0 += xr.x; y1 += xr.y; y2 += xr.z; y3 += xr.w; }
                else      { y0 = xr.x;  y1 = xr.y;  y2 = xr.z;  y3 = xr.w; }
            }
            if (outF) {
                float4 f4; f4.x = y0; f4.y = y1; f4.z = y2; f4.w = y3;
                *(float4*)&outF[row * 256 + col] = f4;
            }
            ushort4 u4;
            u4.x = f2b(y0); u4.y = f2b(y1); u4.z = f2b(y2); u4.w = f2b(y3);
            *(ushort4*)&outB[row * 256 + col] = u4;
        }
    }
}

// ---------------- per-class KV / Ksum reduction (SRC-side token lists) --------
__global__ __launch_bounds__(256) void lft_kv_kernel(
    const ushort* __restrict__ kvab,
    const int* __restrict__ tlist, const int* __restrict__ meta,
    float* kv, float* ksum)
{
    int chunk = blockIdx.x, c = blockIdx.y;
    int b = blockIdx.z >> 3, h = blockIdx.z & 7;
    int off = meta[(b * 8 + c) * 2], n = meta[(b * 8 + c) * 2 + 1];
    int per = (n + KV_NCH - 1) / KV_NCH;
    int s0 = chunk * per;
    int s1 = min(s0 + per, n);
    if (s0 >= s1) return;
    const int* tl = tlist + b * 4800 + off;
    int t = threadIdx.x;
    __shared__ float kb[8][32];
    __shared__ float vb[8][32];
    int od = t >> 3, oe = (t & 7) << 2;
    int lt = t >> 5, ld = t & 31;
    float a0 = 0.f, a1 = 0.f, a2 = 0.f, a3 = 0.f, ak = 0.f;
    for (int s = s0; s < s1; s += 8) {
        float kval = 0.f, vval = 0.f;
        if (s + lt < s1) {
            int tok = tl[s + lt];
            long bse = ((long)b * 4800 + tok) * 512 + h * 32 + ld;
            kval = b2f(kvab[bse]);
            vval = b2f(kvab[bse + 256]);
        }
        __syncthreads();
        kb[lt][ld] = kval;
        vb[lt][ld] = vval;
        __syncthreads();
#pragma unroll
        for (int j = 0; j < 8; j++) {
            float kd = kb[j][od];
            float4 vv = *(const float4*)&vb[j][oe];
            a0 += kd * vv.x; a1 += kd * vv.y; a2 += kd * vv.z; a3 += kd * vv.w;
            ak += kd;
        }
    }
    float* dst = kv + (((long)(b * NPROTO + c) * 8 + h) << 10) + od * 32 + oe;
    atomicAdd(dst + 0, a0);
    atomicAdd(dst + 1, a1);
    atomicAdd(dst + 2, a2);
    atomicAdd(dst + 3, a3);
    if ((t & 7) == 0)
        atomicAdd(ksum + (((long)(b * NPROTO + c) * 8 + h) << 5) + od, ak);
}

// ---------------- kv fp32 [d][e] + ksum → bf16 B-layout [e'][d], e'<48 -------
__global__ __launch_bounds__(256) void lft_kvconv_kernel(
    const float* __restrict__ kvb, const float* __restrict__ ksb,
    ushort* __restrict__ kvt)
{
    int bc = blockIdx.x;          // b*8+c
    int t = threadIdx.x;
    int h = t >> 5, d = t & 31;
    const float* kvsrc = kvb + ((long)bc * 8 + h) * 1024;
    const float* kssrc = ksb + ((long)bc * 8 + h) * 32;
    ushort* dst = kvt + ((long)bc * 8 + h) * 1536;
#pragma unroll
    for (int e = 0; e < 32; e++) dst[e * 32 + d] = f2b(kvsrc[d * 32 + e]);
    dst[32 * 32 + d] = f2b(kssrc[d]);
#pragma unroll
    for (int e = 33; e < 48; e++) dst[e * 32 + d] = 0;
}

// ---------------- msg via MFMA over X-SIDE class-sorted lists ----------------
__global__ __launch_bounds__(256) void lft_msg_kernel(
    const ushort* __restrict__ pq, const ushort* __restrict__ kvt,
    const int* __restrict__ tlist, const int* __restrict__ meta,
    ushort* __restrict__ msg)
{
    int chunk = blockIdx.x, c = blockIdx.y, b = blockIdx.z;
    int off = meta[(b * 8 + c) * 2], n = meta[(b * 8 + c) * 2 + 1];
    int per = (n + MSG_NCH - 1) / MSG_NCH;
    int s0 = chunk * per, s1 = min(s0 + per, n);
    if (s0 >= s1) return;
    const int* tl = tlist + b * 4800 + off;
    int t = threadIdx.x;
    int wave = t >> 6, lane = t & 63;
    int l16 = lane & 15, quad = lane >> 4;
    int bc = b * 8 + c;
    short8 bfr[2][3];
#pragma unroll
    for (int hh = 0; hh < 2; hh++) {
        int h = wave * 2 + hh;
        const ushort* kb = kvt + ((long)bc * 8 + h) * 1536;
#pragma unroll
        for (int nt = 0; nt < 3; nt++)
            bfr[hh][nt] = *(const short8*)&kb[(nt * 16 + l16) * 32 + quad * 8];
    }
    for (int s = s0; s < s1; s += 16) {
        int ia = min(s + l16, s1 - 1);
        int tokA = tl[ia];
        long rowA = (long)b * 4800 + tokA;
#pragma unroll
        for (int hh = 0; hh < 2; hh++) {
            int h = wave * 2 + hh;
            short8 a = *(const short8*)&pq[rowA * 256 + h * 32 + quad * 8];
            floatx4 n0 = {}, n1 = {}, dd = {};
            n0 = __builtin_amdgcn_mfma_f32_16x16x32_bf16(a, bfr[hh][0], n0, 0, 0, 0);
            n1 = __builtin_amdgcn_mfma_f32_16x16x32_bf16(a, bfr[hh][1], n1, 0, 0, 0);
            dd = __builtin_amdgcn_mfma_f32_16x16x32_bf16(a, bfr[hh][2], dd, 0, 0, 0);
#pragma unroll
            for (int r = 0; r < 4; r++) {
                int rowi = s + quad * 4 + r;
                float den = __shfl(dd[r], lane & 48, 64);
                float inv = 1.f / (den + 1e-6f);
                int tokr = __shfl(tokA, quad * 4 + r, 64);
                if (rowi < s1) {
                    long base = ((long)b * 4800 + tokr) * 256 + h * 32;
                    msg[base + l16]      = f2b(n0[r] * inv);
                    msg[base + 16 + l16] = f2b(n1[r] * inv);
                }
            }
        }
    }
}

extern "C" void kernel_launch(void* const* d_in, const int* in_sizes, int n_in,
                              void* d_out, int out_size, void* d_ws, size_t ws_size,
                              hipStream_t stream)
{
    (void)in_sizes; (void)n_in; (void)out_size; (void)ws_size;
    const float* feat0 = (const float*)d_in[0];
    const float* feat1 = (const float*)d_in[1];
    const int*   mask0 = (const int*)d_in[2];
    const int*   mask1 = (const int*)d_in[3];
    const float* f0wo  = (const float*)d_in[4];
    const float* f1wo  = (const float*)d_in[5];
    const float* proto = (const float*)d_in[6];
    const float* Wq = (const float*)d_in[7];
    const float* Wk = (const float*)d_in[8];
    const float* Wv = (const float*)d_in[9];
    const float* Wm = (const float*)d_in[10];
    const float* W1 = (const float*)d_in[11];
    const float* W2 = (const float*)d_in[12];
    const float* g1 = (const float*)d_in[13];
    const float* b1 = (const float*)d_in[14];
    const float* g2 = (const float*)d_in[15];
    const float* b2 = (const float*)d_in[16];
    float* out = (float*)d_out;
    float* ws = (float*)d_ws;

    // ---- workspace layout ----
    const long FSZ = 9830400L;             // 8*4800*256
    float* fa = ws;                        // fp32 master feat0
    float* fb = ws + FSZ;                  // fp32 master feat1
    // region [ws+2FSZ, ws+4FSZ) = 78.6MB, phase-aliased:
    ushort* kvab  = (ushort*)(ws + 2 * FSZ);  // phase1: [38400,512] [phi_k|v]
    ushort* qb    = (ushort*)(ws + 3 * FSZ);  // phase1: [38400,256] phi_q
    ushort* hid2x = (ushort*)(ws + 2 * FSZ);  // phase2: [76800,512] relu-hid
    ushort* ub  = (ushort*)(ws + 4 * FSZ);
    ushort* fa_bf = ub;                    // bf16 shadow of fa
    ushort* fb_bf = ub + FSZ;              // bf16 shadow of fb
    ushort* msg0  = ub + 2 * FSZ;          // msg side0 (in-place LN1)
    ushort* msg1  = ub + 3 * FSZ;          // msg side1
    ushort* wb    = ub + 4 * FSZ;          // bf16 transposed weights
    ushort* wb1   = wb + 16 * 65536;       // W1^T per layer [512][512]
    ushort* wb2   = wb1 + 4 * 262144;      // W2^T per layer [256][512]
    ushort* kvt   = wb2 + 4 * 131072;      // [64][8][48][32] bf16
    float* kvb = (float*)(kvt + 786432);   // [B,NP,H,D,D] = 524288 f
    float* ksb = kvb + 524288;             // [B,NP,H,D]   = 16384 f
    int* cls0 = (int*)(ksb + 16384);
    int* cls1 = cls0 + 38400;
    int* tl0  = cls1 + 38400;
    int* tl1  = tl0 + 38400;
    int* meta = tl1 + 38400;               // [2][8][8][2] (off,cnt)

    // one-time per launch
    lft_wconv_kernel<<<dim3(8, 8, 16), 256, 0, stream>>>(Wq, Wk, Wv, Wm, 256, 256, 4, wb);
    lft_wconv_kernel<<<dim3(16, 16, 4), 256, 0, stream>>>(W1, W1, W1, W1, 512, 512, 1, wb1);
    lft_wconv_kernel<<<dim3(16, 8, 4), 256, 0, stream>>>(W2, W2, W2, W2, 512, 256, 1, wb2);
    lft_cast_kernel<<<19200, 256, 0, stream>>>(feat0, feat1, fa_bf, fb_bf);
    hipMemcpyAsync(out + 20352000L, proto, 2048 * 4, hipMemcpyDeviceToDevice, stream);
    lft_class_kernel<<<19200, 256, 0, stream>>>(f0wo, f1wo, mask0, mask1, proto,
                                                out, cls0, cls1);
    lft_sort_kernel<<<16, 256, 0, stream>>>(cls0, cls1, tl0, tl1, meta);

    for (int li = 0; li < 4; li++) {
        const ushort* wq = wb + (size_t)(li * 4 + 0) * 65536;  // wq|wk|wv contig
        const ushort* wk = wb + (size_t)(li * 4 + 1) * 65536;  // wk|wv contig
        const ushort* wm = wb + (size_t)(li * 4 + 3) * 65536;
        const ushort* w1 = wb1 + (size_t)li * 262144;
        const ushort* w2 = wb2 + (size_t)li * 131072;
        const float* g1p = g1 + li * 256; const float* b1p = b1 + li * 256;
        const float* g2p = g2 + li * 256; const float* b2p = b2 + li * 256;
        dim3 blk(256);

        // phase1: q/k/v projections + per-class kv stats + msg (one feature side)
        auto phase1 = [&](ushort* x_bf, ushort* s_bf,
                          const int* tlx, const int* mtx,
                          const int* tls, const int* mts, ushort* msgX) {
            if (x_bf == s_bf) {
                lft_mfma_gemm<<<dim3(6, 300), blk, 0, stream>>>(x_bf, x_bf, 256, wq,
                    nullptr, qb, 256, 256, 1, 512, kvab, 512, 256, nullptr, nullptr, MBIG);
            } else {
                lft_mfma_gemm<<<dim3(2, 300), blk, 0, stream>>>(x_bf, x_bf, 256, wq,
                    nullptr, qb, 256, 256, 1, 256, nullptr, 0, 0, nullptr, nullptr, MBIG);
                lft_mfma_gemm<<<dim3(4, 300), blk, 0, stream>>>(s_bf, s_bf, 256, wk,
                    nullptr, kvab, 512, 256, 1, 256, nullptr, 0, 0, nullptr, nullptr, MBIG);
            }
            hipMemsetAsync(kvb, 0, (524288 + 16384) * 4, stream);
            lft_kv_kernel<<<dim3(KV_NCH, 8, 64), blk, 0, stream>>>(kvab, tls, mts, kvb, ksb);
            lft_kvconv_kernel<<<64, blk, 0, stream>>>(kvb, ksb, kvt);
            lft_msg_kernel<<<dim3(MSG_NCH, 8, 8), blk, 0, stream>>>(qb, kvt, tlx, mtx, msgX);
        };

        const float* ra = (li == 0) ? feat0 : fa;
        const float* rb = (li == 0) ? feat1 : fb;
        float* oa = (li == 3) ? out : fa;
        float* ob = (li == 3) ? (out + FSZ) : fb;

        if ((li & 1) == 0) {
            // ---- self-self: both sides' phase1, then MERGED phase2 ----
            phase1(fa_bf, fa_bf, tl0, meta,       tl0, meta,       msg0);
            phase1(fb_bf, fb_bf, tl1, meta + 128, tl1, meta + 128, msg1);
            // merged LN1 (in-place), 1200 blocks
            lft_gemm_ln<<<1200, blk, 0, stream>>>(msg0, msg1, wm, 256, g1p, b1p,
                nullptr, nullptr, nullptr, nullptr, nullptr, nullptr, msg0, msg1, 38400L);
            // merged W1 -> hid2x [76800,512], 2400 blocks
            lft_mfma_gemm<<<dim3(4, 600), blk, 0, stream>>>(fa_bf, msg0, 256, w1,
                nullptr, hid2x, 512, 512, 2, 512, nullptr, 0, 0, fb_bf, msg1, 38400L);
            // merged LN2+resid, 1200 blocks
            lft_gemm_ln<<<1200, blk, 0, stream>>>(hid2x, hid2x + 38400L * 512, w2, 512,
                g2p, b2p, ra, rb, cls0, cls1, oa, ob, fa_bf, fb_bf, 38400L);
        } else {
            // ---- cross-self: sequential (side B depends on updated side A) ----
            phase1(fa_bf, fb_bf, tl0, meta, tl1, meta + 128, msg0);
            lft_gemm_ln<<<600, blk, 0, stream>>>(msg0, nullptr, wm, 256, g1p, b1p,
                nullptr, nullptr, nullptr, nullptr, nullptr, nullptr, msg0, nullptr, MBIG);
            lft_mfma_gemm<<<dim3(4, 300), blk, 0, stream>>>(fa_bf, msg0, 256, w1,
                nullptr, hid2x, 512, 512, 2, 512, nullptr, 0, 0, nullptr, nullptr, MBIG);
            lft_gemm_ln<<<600, blk, 0, stream>>>(hid2x, nullptr, w2, 512, g2p, b2p,
                ra, nullptr, cls0, nullptr, oa, nullptr, fa_bf, nullptr, MBIG);

            phase1(fb_bf, fa_bf, tl1, meta + 128, tl0, meta, msg1);
            lft_gemm_ln<<<600, blk, 0, stream>>>(msg1, nullptr, wm, 256, g1p, b1p,
                nullptr, nullptr, nullptr, nullptr, nullptr, nullptr, msg1, nullptr, MBIG);
            lft_mfma_gemm<<<dim3(4, 300), blk, 0, stream>>>(fb_bf, msg1, 256, w1,
                nullptr, hid2x, 512, 512, 2, 512, nullptr, 0, 0, nullptr, nullptr, MBIG);
            lft_gemm_ln<<<600, blk, 0, stream>>>(hid2x, nullptr, w2, 512, g2p, b2p,
                rb, nullptr, cls1, nullptr, ob, nullptr, fb_bf, nullptr, MBIG);
        }
    }
}